// Round 1
// baseline (6144.165 us; speedup 1.0000x reference)
//
#include <hip/hip_runtime.h>
#include <hip/hip_bf16.h>
#include <math.h>

#define NND 20000      // nodes
#define NE  320000     // edges
#define NF  128        // feature width (n_input == n_hidden)
#define DIN 262        // 2*NF + 6
#define EPS 1e-5f
#define TE  32         // edges per tile
#define NT  256        // threads per block
#define NTILES (NE / TE)   // 10000
#define XS  132        // padded LDS row stride (floats)

__device__ __forceinline__ float psif(float z) {
    return copysignf(log1pf(fabsf(z)), z);
}
__device__ __forceinline__ float sigm(float z) {
    return 1.f / (1.f + expf(-z));
}

// ---------------------------------------------------------------------------
// Pass 1: compute hpre = m @ W1 per edge, accumulate per-channel sum/sumsq
// (BN statistics). hpre is NOT stored (recomputed in edge_pass).
// ---------------------------------------------------------------------------
__global__ __launch_bounds__(NT)
void stats_pass(const float* __restrict__ x,
                const int* __restrict__ ei,
                const float* __restrict__ eattr,
                const float* __restrict__ W1l,
                float* __restrict__ gstats)
{
    __shared__ float xi[TE * XS];
    __shared__ float xj[TE * XS];
    __shared__ float bs[32 * NF];
    __shared__ float eat[TE][4];
    __shared__ float ndl[TE][2];
    __shared__ int ridx[TE], cidx[TE];
    __shared__ float red[3][16][16];

    const int t  = threadIdx.x;
    const int es = t >> 4;          // 0..15 -> edges 2es, 2es+1
    const int cg = t & 15;          // channel group
    const int c0 = cg * 8;
    const int le = t >> 3;          // 0..31 (load layout: edge)
    const int q  = t & 7;           // 0..7  (load layout: 8 threads/edge)

    float ssum[8], ssq[8];
    #pragma unroll
    for (int i = 0; i < 8; ++i) { ssum[i] = 0.f; ssq[i] = 0.f; }

    for (int tile = blockIdx.x; tile < NTILES; tile += gridDim.x) {
        const int e0 = tile * TE;
        __syncthreads();  // protect LDS vs previous iteration's readers
        if (t < TE)            ridx[t] = ei[e0 + t];
        else if (t < 2 * TE)   cidx[t - TE] = ei[NE + e0 + (t - TE)];
        if (t < 128) { int e = t >> 2, j = t & 3; eat[e][j] = eattr[(size_t)(e0 + e) * 4 + j]; }
        __syncthreads();

        // gather x_i/x_j rows into LDS, compute Minkowski norms/dots
        {
            const int r = ridx[le], c = cidx[le];
            const float4* xr = (const float4*)(x + (size_t)r * NF);
            const float4* xc = (const float4*)(x + (size_t)c * NF);
            float nrm = 0.f, dot = 0.f;
            #pragma unroll
            for (int j = 0; j < 4; ++j) {
                int cc = q + 8 * j;
                float4 a = xr[cc], b = xc[cc];
                ((float4*)(xi + le * XS))[cc] = a;
                ((float4*)(xj + le * XS))[cc] = b;
                float dx = a.x-b.x, dy = a.y-b.y, dz = a.z-b.z, dw = a.w-b.w;
                nrm -= dx*dx + dy*dy + dz*dz + dw*dw;
                dot -= a.x*b.x + a.y*b.y + a.z*b.z + a.w*b.w;
                if (cc == 0) { nrm += 2.f*dx*dx; dot += 2.f*a.x*b.x; }  // +metric on comp 0
            }
            #pragma unroll
            for (int m = 1; m < 8; m <<= 1) {
                nrm += __shfl_xor(nrm, m);
                dot += __shfl_xor(dot, m);
            }
            if (q == 0) { ndl[le][0] = psif(nrm); ndl[le][1] = psif(dot); }
        }

        float acc[2][8];
        #pragma unroll
        for (int j = 0; j < 2; ++j)
            #pragma unroll
            for (int i = 0; i < 8; ++i) acc[j][i] = 0.f;

        // K = 0..255 in 8 slabs of 32 (xi rows 0..127, xj rows 128..255)
        for (int s = 0; s < 8; ++s) {
            __syncthreads();
            {
                const float4* src = (const float4*)(W1l + (size_t)(s * 32 + le) * NF);
                float4* dst = (float4*)(bs + le * NF);
                #pragma unroll
                for (int j = 0; j < 4; ++j) { int cc = q + 8 * j; dst[cc] = src[cc]; }
            }
            __syncthreads();
            const float* A = (s < 4) ? xi : xj;
            const float* Ar0 = A + (2 * es) * XS + (s & 3) * 32;
            const float* Ar1 = Ar0 + XS;
            #pragma unroll 4
            for (int k = 0; k < 32; ++k) {
                float a0 = Ar0[k], a1 = Ar1[k];
                const float* brow = bs + k * NF + c0;
                #pragma unroll
                for (int i = 0; i < 8; ++i) {
                    float b = brow[i];
                    acc[0][i] = fmaf(a0, b, acc[0][i]);
                    acc[1][i] = fmaf(a1, b, acc[1][i]);
                }
            }
        }
        // tail K = 256..261: edge_attr(4), norms, dots
        {
            const int eA = 2 * es, eB = eA + 1;
            #pragma unroll
            for (int r = 0; r < 6; ++r) {
                const float* wrow = W1l + (size_t)(256 + r) * NF + c0;
                float f0 = (r < 4) ? eat[eA][r] : ndl[eA][r - 4];
                float f1 = (r < 4) ? eat[eB][r] : ndl[eB][r - 4];
                #pragma unroll
                for (int i = 0; i < 8; ++i) {
                    float b = wrow[i];
                    acc[0][i] = fmaf(f0, b, acc[0][i]);
                    acc[1][i] = fmaf(f1, b, acc[1][i]);
                }
            }
        }
        #pragma unroll
        for (int j = 0; j < 2; ++j)
            #pragma unroll
            for (int i = 0; i < 8; ++i) {
                float v = acc[j][i];
                ssum[i] += v;
                ssq[i]  = fmaf(v, v, ssq[i]);
            }
    }

    // reduce stats: same-cg lanes are stride-16 within a wave
    #pragma unroll
    for (int i = 0; i < 8; ++i) {
        ssum[i] += __shfl_xor(ssum[i], 16); ssum[i] += __shfl_xor(ssum[i], 32);
        ssq[i]  += __shfl_xor(ssq[i], 16);  ssq[i]  += __shfl_xor(ssq[i], 32);
    }
    const int wv = t >> 6, ln = t & 63;
    __syncthreads();
    if (wv > 0 && ln < 16) {
        #pragma unroll
        for (int i = 0; i < 8; ++i) { red[wv-1][ln][i] = ssum[i]; red[wv-1][ln][8+i] = ssq[i]; }
    }
    __syncthreads();
    if (wv == 0 && ln < 16) {
        #pragma unroll
        for (int i = 0; i < 8; ++i) {
            float s = ssum[i] + red[0][ln][i] + red[1][ln][i] + red[2][ln][i];
            float qq = ssq[i] + red[0][ln][8+i] + red[1][ln][8+i] + red[2][ln][8+i];
            atomicAdd(&gstats[ln * 8 + i], s);
            atomicAdd(&gstats[128 + ln * 8 + i], qq);
        }
    }
}

// ---------------------------------------------------------------------------
// BN finalize: scale = gamma * rsqrt(var+eps); shift = beta - mu*scale
// ---------------------------------------------------------------------------
__global__ void bn_finalize(const float* __restrict__ gstats,
                            const float* __restrict__ gamma,
                            const float* __restrict__ beta,
                            float* __restrict__ scsh)
{
    int c = threadIdx.x;
    float mu  = gstats[c] * (1.f / NE);
    float var = gstats[128 + c] * (1.f / NE) - mu * mu;
    var = fmaxf(var, 0.f);
    float inv = rsqrtf(var + EPS);
    float scale = gamma[c] * inv;
    scsh[c]      = scale;
    scsh[128 + c] = beta[c] - mu * scale;
}

// ---------------------------------------------------------------------------
// Pass 2: recompute hpre, then BN->ReLU->W2->gate(Wm)->Wa->Wb->scatter-add
// ---------------------------------------------------------------------------
__global__ __launch_bounds__(NT)
void edge_pass(const float* __restrict__ x,
               float* __restrict__ xn,
               const int* __restrict__ ei,
               const float* __restrict__ eattr,
               const float* __restrict__ W1l,
               const float* __restrict__ scsh,
               const float* __restrict__ W2l, const float* __restrict__ b2l,
               const float* __restrict__ Wal, const float* __restrict__ bal,
               const float* __restrict__ Wbl, const float* __restrict__ Wml,
               const float* __restrict__ bml)
{
    __shared__ float ab[2 * TE * XS];   // xi|xj, later reused as bufA|bufB
    __shared__ float bs[32 * NF];
    __shared__ float eat[TE][4];
    __shared__ float ndl[TE][2];
    __shared__ int ridx[TE], cidx[TE];
    __shared__ float scs[NF], sfs[NF], b2s[NF], bas[NF], wms[NF], wbs[NF];

    const int t  = threadIdx.x;
    const int es = t >> 4, cg = t & 15, c0 = cg * 8;
    const int le = t >> 3, q  = t & 7;
    float* xi = ab;
    float* xj = ab + TE * XS;

    if (t < NF) {
        scs[t] = scsh[t];      sfs[t] = scsh[NF + t];
        b2s[t] = b2l[t];       bas[t] = bal[t];
        wms[t] = Wml[t];       wbs[t] = Wbl[t];
    }
    const float bmv = bml[0];

    for (int tile = blockIdx.x; tile < NTILES; tile += gridDim.x) {
        const int e0 = tile * TE;
        __syncthreads();
        if (t < TE)            ridx[t] = ei[e0 + t];
        else if (t < 2 * TE)   cidx[t - TE] = ei[NE + e0 + (t - TE)];
        if (t < 128) { int e = t >> 2, j = t & 3; eat[e][j] = eattr[(size_t)(e0 + e) * 4 + j]; }
        __syncthreads();

        // gather + norms/dots
        {
            const int r = ridx[le], c = cidx[le];
            const float4* xr = (const float4*)(x + (size_t)r * NF);
            const float4* xc = (const float4*)(x + (size_t)c * NF);
            float nrm = 0.f, dot = 0.f;
            #pragma unroll
            for (int j = 0; j < 4; ++j) {
                int cc = q + 8 * j;
                float4 a = xr[cc], b = xc[cc];
                ((float4*)(xi + le * XS))[cc] = a;
                ((float4*)(xj + le * XS))[cc] = b;
                float dx = a.x-b.x, dy = a.y-b.y, dz = a.z-b.z, dw = a.w-b.w;
                nrm -= dx*dx + dy*dy + dz*dz + dw*dw;
                dot -= a.x*b.x + a.y*b.y + a.z*b.z + a.w*b.w;
                if (cc == 0) { nrm += 2.f*dx*dx; dot += 2.f*a.x*b.x; }
            }
            #pragma unroll
            for (int m = 1; m < 8; m <<= 1) {
                nrm += __shfl_xor(nrm, m);
                dot += __shfl_xor(dot, m);
            }
            if (q == 0) { ndl[le][0] = psif(nrm); ndl[le][1] = psif(dot); }
        }

        float acc[2][8];
        #pragma unroll
        for (int j = 0; j < 2; ++j)
            #pragma unroll
            for (int i = 0; i < 8; ++i) acc[j][i] = 0.f;

        // GEMM0: hpre = m @ W1
        for (int s = 0; s < 8; ++s) {
            __syncthreads();
            {
                const float4* src = (const float4*)(W1l + (size_t)(s * 32 + le) * NF);
                float4* dst = (float4*)(bs + le * NF);
                #pragma unroll
                for (int j = 0; j < 4; ++j) { int cc = q + 8 * j; dst[cc] = src[cc]; }
            }
            __syncthreads();
            const float* A = (s < 4) ? xi : xj;
            const float* Ar0 = A + (2 * es) * XS + (s & 3) * 32;
            const float* Ar1 = Ar0 + XS;
            #pragma unroll 4
            for (int k = 0; k < 32; ++k) {
                float a0 = Ar0[k], a1 = Ar1[k];
                const float* brow = bs + k * NF + c0;
                #pragma unroll
                for (int i = 0; i < 8; ++i) {
                    float b = brow[i];
                    acc[0][i] = fmaf(a0, b, acc[0][i]);
                    acc[1][i] = fmaf(a1, b, acc[1][i]);
                }
            }
        }
        {   // tail K = 256..261
            const int eA = 2 * es, eB = eA + 1;
            #pragma unroll
            for (int r = 0; r < 6; ++r) {
                const float* wrow = W1l + (size_t)(256 + r) * NF + c0;
                float f0 = (r < 4) ? eat[eA][r] : ndl[eA][r - 4];
                float f1 = (r < 4) ? eat[eB][r] : ndl[eB][r - 4];
                #pragma unroll
                for (int i = 0; i < 8; ++i) {
                    float b = wrow[i];
                    acc[0][i] = fmaf(f0, b, acc[0][i]);
                    acc[1][i] = fmaf(f1, b, acc[1][i]);
                }
            }
        }

        // BN + ReLU -> hid; store into bufA (reuses xi space, so sync first)
        float hid0[8], hid1[8];
        #pragma unroll
        for (int i = 0; i < 8; ++i) {
            float sc = scs[c0 + i], sf = sfs[c0 + i];
            hid0[i] = fmaxf(fmaf(acc[0][i], sc, sf), 0.f);
            hid1[i] = fmaxf(fmaf(acc[1][i], sc, sf), 0.f);
        }
        __syncthreads();   // all xi/xj reads of GEMM0 complete
        #pragma unroll
        for (int i = 0; i < 8; ++i) {
            xi[(2 * es)     * XS + c0 + i] = hid0[i];
            xi[(2 * es + 1) * XS + c0 + i] = hid1[i];
        }

        // GEMM1: mij_raw = hid @ W2 (+b2, ReLU)
        #pragma unroll
        for (int j = 0; j < 2; ++j)
            #pragma unroll
            for (int i = 0; i < 8; ++i) acc[j][i] = 0.f;
        for (int s = 0; s < 4; ++s) {
            __syncthreads();
            {
                const float4* src = (const float4*)(W2l + (size_t)(s * 32 + le) * NF);
                float4* dst = (float4*)(bs + le * NF);
                #pragma unroll
                for (int j = 0; j < 4; ++j) { int cc = q + 8 * j; dst[cc] = src[cc]; }
            }
            __syncthreads();
            const float* Ar0 = xi + (2 * es) * XS + s * 32;
            const float* Ar1 = Ar0 + XS;
            #pragma unroll 4
            for (int k = 0; k < 32; ++k) {
                float a0 = Ar0[k], a1 = Ar1[k];
                const float* brow = bs + k * NF + c0;
                #pragma unroll
                for (int i = 0; i < 8; ++i) {
                    float b = brow[i];
                    acc[0][i] = fmaf(a0, b, acc[0][i]);
                    acc[1][i] = fmaf(a1, b, acc[1][i]);
                }
            }
        }
        float mj0[8], mj1[8];
        float wd0 = 0.f, wd1 = 0.f;
        #pragma unroll
        for (int i = 0; i < 8; ++i) {
            float bb = b2s[c0 + i];
            float v0 = fmaxf(acc[0][i] + bb, 0.f);
            float v1 = fmaxf(acc[1][i] + bb, 0.f);
            mj0[i] = v0; mj1[i] = v1;
            float wm = wms[c0 + i];
            wd0 = fmaf(v0, wm, wd0);
            wd1 = fmaf(v1, wm, wd1);
        }
        #pragma unroll
        for (int m = 1; m < 16; m <<= 1) { wd0 += __shfl_xor(wd0, m); wd1 += __shfl_xor(wd1, m); }
        const float w0 = sigm(wd0 + bmv), w1 = sigm(wd1 + bmv);

        // write mij_raw into bufB (xj space; xj not read since pre-bufA sync)
        #pragma unroll
        for (int i = 0; i < 8; ++i) {
            xj[(2 * es)     * XS + c0 + i] = mj0[i];
            xj[(2 * es + 1) * XS + c0 + i] = mj1[i];
        }

        // GEMM2: t = relu(w * (mij_raw @ Wa) + ba); s = t . Wb
        #pragma unroll
        for (int j = 0; j < 2; ++j)
            #pragma unroll
            for (int i = 0; i < 8; ++i) acc[j][i] = 0.f;
        for (int s = 0; s < 4; ++s) {
            __syncthreads();
            {
                const float4* src = (const float4*)(Wal + (size_t)(s * 32 + le) * NF);
                float4* dst = (float4*)(bs + le * NF);
                #pragma unroll
                for (int j = 0; j < 4; ++j) { int cc = q + 8 * j; dst[cc] = src[cc]; }
            }
            __syncthreads();
            const float* Ar0 = xj + (2 * es) * XS + s * 32;
            const float* Ar1 = Ar0 + XS;
            #pragma unroll 4
            for (int k = 0; k < 32; ++k) {
                float a0 = Ar0[k], a1 = Ar1[k];
                const float* brow = bs + k * NF + c0;
                #pragma unroll
                for (int i = 0; i < 8; ++i) {
                    float b = brow[i];
                    acc[0][i] = fmaf(a0, b, acc[0][i]);
                    acc[1][i] = fmaf(a1, b, acc[1][i]);
                }
            }
        }
        float sd0 = 0.f, sd1 = 0.f;
        #pragma unroll
        for (int i = 0; i < 8; ++i) {
            float ba_ = bas[c0 + i];
            float v0 = fmaxf(fmaf(w0, acc[0][i], ba_), 0.f);
            float v1 = fmaxf(fmaf(w1, acc[1][i], ba_), 0.f);
            float wb = wbs[c0 + i];
            sd0 = fmaf(v0, wb, sd0);
            sd1 = fmaf(v1, wb, sd1);
        }
        #pragma unroll
        for (int m = 1; m < 16; m <<= 1) { sd0 += __shfl_xor(sd0, m); sd1 += __shfl_xor(sd1, m); }

        // scatter: x_next[row] += clip(x_diff * s, +-100)
        #pragma unroll
        for (int j = 0; j < 2; ++j) {
            const int e = 2 * es + j;
            const float sv = j ? sd1 : sd0;
            const int r = ridx[e], cI = cidx[e];
            const float* xr = x + (size_t)r  * NF + c0;
            const float* xc = x + (size_t)cI * NF + c0;
            float* dst = xn + (size_t)r * NF + c0;
            #pragma unroll
            for (int i = 0; i < 8; ++i) {
                float d = xr[i] - xc[i];
                float tr = fminf(fmaxf(d * sv, -100.f), 100.f);
                atomicAdd(dst + i, tr);
            }
        }
    }
}

// ---------------------------------------------------------------------------
__global__ __launch_bounds__(NT)
void copyk(const float* __restrict__ src, float* __restrict__ dst, int n4)
{
    int i = blockIdx.x * NT + threadIdx.x;
    if (i < n4) ((float4*)dst)[i] = ((const float4*)src)[i];
}

__global__ __launch_bounds__(NT)
void finalk(const float* __restrict__ x, const float* __restrict__ We,
            const float* __restrict__ be, float* __restrict__ out)
{
    int gw = (blockIdx.x * NT + threadIdx.x) >> 6;  // one wave per node
    int ln = threadIdx.x & 63;
    if (gw >= NND) return;
    const float* xr = x + (size_t)gw * NF;
    float a0 = xr[ln], a1 = xr[ln + 64];
    float o0 = a0 * We[ln * 2]     + a1 * We[(ln + 64) * 2];
    float o1 = a0 * We[ln * 2 + 1] + a1 * We[(ln + 64) * 2 + 1];
    #pragma unroll
    for (int m = 1; m < 64; m <<= 1) { o0 += __shfl_xor(o0, m); o1 += __shfl_xor(o1, m); }
    if (ln == 0) {
        out[gw * 2]     = sigm(o0 + be[0]);
        out[gw * 2 + 1] = sigm(o1 + be[1]);
    }
}

// ---------------------------------------------------------------------------
extern "C" void kernel_launch(void* const* d_in, const int* in_sizes, int n_in,
                              void* d_out, int out_size, void* d_ws, size_t ws_size,
                              hipStream_t stream) {
    const float* x   = (const float*)d_in[0];
    const int*   ei  = (const int*)d_in[1];
    const float* ea  = (const float*)d_in[2];
    const float* W1  = (const float*)d_in[3];
    const float* ga  = (const float*)d_in[4];
    const float* bet = (const float*)d_in[5];
    const float* W2  = (const float*)d_in[6];
    const float* b2  = (const float*)d_in[7];
    const float* Wa  = (const float*)d_in[8];
    const float* ba  = (const float*)d_in[9];
    const float* Wb  = (const float*)d_in[10];
    const float* Wm  = (const float*)d_in[11];
    const float* bm  = (const float*)d_in[12];
    const float* We  = (const float*)d_in[13];
    const float* be  = (const float*)d_in[14];
    float* out = (float*)d_out;

    float* ws    = (float*)d_ws;
    float* gstats = ws;            // 256 floats (sum | sumsq)
    float* scsh   = ws + 256;      // 256 floats (scale | shift)
    float* xA     = ws + 512;
    float* xB     = xA + (size_t)NND * NF;

    const int NB = 2500;           // grid-stride blocks for edge passes
    const float* xc = x;
    float* buf[2] = { xA, xB };

    for (int l = 0; l < 3; ++l) {
        float* xn = buf[l & 1];
        hipMemsetAsync(gstats, 0, 256 * sizeof(float), stream);
        copyk<<<(NND * NF / 4 + NT - 1) / NT, NT, 0, stream>>>(xc, xn, NND * NF / 4);
        stats_pass<<<NB, NT, 0, stream>>>(xc, ei, ea, W1 + (size_t)l * DIN * NF, gstats);
        bn_finalize<<<1, 128, 0, stream>>>(gstats, ga + l * NF, bet + l * NF, scsh);
        edge_pass<<<NB, NT, 0, stream>>>(xc, xn, ei, ea, W1 + (size_t)l * DIN * NF, scsh,
                                         W2 + (size_t)l * NF * NF, b2 + l * NF,
                                         Wa + (size_t)l * NF * NF, ba + l * NF,
                                         Wb + l * NF, Wm + l * NF, bm + l);
        xc = xn;
    }
    finalk<<<(NND * 64 + NT - 1) / NT, NT, 0, stream>>>(xc, We, be, out);
}